// Round 4
// baseline (55.476 us; speedup 1.0000x reference)
//
#include <hip/hip_runtime.h>
#include <math.h>

#define W 384
#define H 384
#define NB 32
#define NPIX (W*H)

#define BAND 32
#define NBANDS (H/BAND)                 // 12
#define NBLK1 (NB*NBANDS)               // 384 blocks, 384 threads each

#define RC 8                            // rows per wave in K2
#define CPI 72                          // K2 blocks per image: 6 colgroups * 48 rowchunks / 4 waves
#define NBLK2 (NB*CPI)                  // 2304 blocks, 256 threads each

// ---------------------------------------------------------------------------
// K1: band-local 2D prefix. S[y][x] = sum_{y'=band_start..y} sum_{x'<=x} m[y'][x']
// ---------------------------------------------------------------------------
__global__ __launch_bounds__(384) void band_prefix_kernel(
    const float* __restrict__ mask, float* __restrict__ S)
{
    __shared__ float lds[BAND][W];      // 49,152 B

    const int tid  = threadIdx.x;
    const int wave = tid >> 6;
    const int lane = tid & 63;
    const int bid  = blockIdx.x;
    const int b    = (bid & 7) + 8 * ((bid >> 3) / NBANDS);   // XCD swizzle: img%8 == XCD
    const int band = (bid >> 3) % NBANDS;
    const int y0   = band * BAND;

    const float* mimg = mask + (size_t)b * NPIX;
    float*       Simg = S    + (size_t)b * NPIX;
    const int x0 = lane * 6;

    // preload this wave's rows (rows wave, wave+6, ... within band) — independent loads
    float2 q[6][3];
    #pragma unroll
    for (int i = 0; i < 6; ++i) {
        const int r = wave + i * 6;
        if (r < BAND) {
            const float2* src = (const float2*)(mimg + (size_t)(y0 + r) * W + x0);
            q[i][0] = src[0]; q[i][1] = src[1]; q[i][2] = src[2];
        }
    }
    // row-prefix each preloaded row into LDS
    #pragma unroll
    for (int i = 0; i < 6; ++i) {
        const int r = wave + i * 6;
        if (r < BAND) {
            const float v0=q[i][0].x, v1=q[i][0].y, v2=q[i][1].x,
                        v3=q[i][1].y, v4=q[i][2].x, v5=q[i][2].y;
            const float s0=v0, s1=s0+v1, s2=s1+v2, s3=s2+v3, s4=s3+v4, s5=s4+v5;
            float ss = s5;
            #pragma unroll
            for (int d = 1; d < 64; d <<= 1) {
                float t = __shfl_up(ss, d);
                if (lane >= d) ss += t;
            }
            const float base = ss - s5;
            float2* dst = (float2*)&lds[r][x0];
            dst[0] = make_float2(base+s0, base+s1);
            dst[1] = make_float2(base+s2, base+s3);
            dst[2] = make_float2(base+s4, base+s5);
        }
    }
    __syncthreads();

    // column accumulate (tid = column), coalesced stores
    float acc = 0.0f;
    float* dst = Simg + (size_t)y0 * W + tid;
    #pragma unroll 4
    for (int r = 0; r < BAND; ++r) {
        acc += lds[r][tid];
        dst[(size_t)r * W] = acc;
    }
}

// ---------------------------------------------------------------------------
// K2: fused loss. 1 col/lane, 8 rows/wave, 4 independent waves/block.
// Box sums = 4..6 coalesced taps from S. No LDS in the hot loop.
// ---------------------------------------------------------------------------
__global__ __launch_bounds__(256) void loss_kernel(
    const float* __restrict__ pred, const float* __restrict__ mask,
    const float* __restrict__ S, float* __restrict__ partials)
{
    const int tid  = threadIdx.x;
    const int wave = tid >> 6;
    const int lane = tid & 63;
    const int bid  = blockIdx.x;
    const int b    = (bid & 7) + 8 * ((bid >> 3) / CPI);
    const int qq   = (bid >> 3) % CPI;
    const int widx = qq * 4 + wave;          // 0..287
    const int cg   = widx % 6;
    const int rc   = widx / 6;               // 0..47
    const int x    = cg * 64 + lane;
    const int yA   = rc * RC;

    const float* Simg = S    + (size_t)b * NPIX;
    const float* mimg = mask + (size_t)b * NPIX;
    const float* pimg = pred + (size_t)b * NPIX;

    // per-lane clamped tap columns (loop-invariant)
    const int   xR3  = min(x + 1,  W-1), xL3  = max(x - 2,  0);
    const int   xR15 = min(x + 7,  W-1), xL15 = max(x - 8,  0);
    const int   xR31 = min(x + 15, W-1), xL31 = max(x - 16, 0);
    const float f3   = (x >= 2)  ? 1.0f : 0.0f;
    const float f15  = (x >= 8)  ? 1.0f : 0.0f;
    const float f31  = (x >= 16) ? 1.0f : 0.0f;

    float pw=0.f, pi=0.f, pu=0.f, pb=0.f, pm=0.f;

    for (int y = yA; y < yA + RC; ++y) {
        auto box = [&](int r, int xR, int xL, float fL) -> float {
            const int y1  = min(y + r, H-1);
            const int y0r = y - r - 1;
            const float* r1 = Simg + (size_t)y1 * W;
            float v = r1[xR] - fL * r1[xL];
            if (y0r >= 0) {                                   // wave-uniform
                const float* r0 = Simg + (size_t)y0r * W;
                v -= r0[xR] - fL * r0[xL];
                if ((y0r >> 5) != (y1 >> 5)) {                // band crossing
                    const float* rt = Simg + (size_t)(y0r | (BAND-1)) * W;
                    v += rt[xR] - fL * rt[xL];
                }
            }
            return v;
        };
        const float b3  = box(1,  xR3,  xL3,  f3);
        const float b15 = box(7,  xR15, xL15, f15);
        const float b31 = box(15, xR31, xL31, f31);

        const float m = mimg[(size_t)y*W + x];
        const float p = pimg[(size_t)y*W + x];
        const float w = fabsf(b3*(1.0f/9.0f)   - m)
                      + fabsf(b15*(1.0f/225.0f) - m)
                      + fabsf(b31*(1.0f/961.0f) - m);
        const float weit = 1.0f + 0.5f*w*m;
        pw += weit;
        pi += p*m*weit;
        pu += (p+m)*weit;
        pb -= m*__logf(p) + (1.0f - m)*__logf(1.0f - p);
        pm += fabsf(p - m);
    }

    // deterministic wave butterfly
    #pragma unroll
    for (int off = 32; off >= 1; off >>= 1) {
        pw += __shfl_xor(pw, off);
        pi += __shfl_xor(pi, off);
        pu += __shfl_xor(pu, off);
        pb += __shfl_xor(pb, off);
        pm += __shfl_xor(pm, off);
    }
    __shared__ float red[4][5];
    if (lane == 0) {
        red[wave][0]=pw; red[wave][1]=pi; red[wave][2]=pu; red[wave][3]=pb; red[wave][4]=pm;
    }
    __syncthreads();
    if (tid == 0) {
        float o0=0,o1=0,o2=0,o3=0,o4=0;
        #pragma unroll
        for (int wv = 0; wv < 4; ++wv) {
            o0+=red[wv][0]; o1+=red[wv][1]; o2+=red[wv][2]; o3+=red[wv][3]; o4+=red[wv][4];
        }
        float* o = partials + (size_t)bid * 8;
        o[0]=o0; o[1]=o1; o[2]=o2; o[3]=o3; o[4]=o4;
    }
}

// ---------------------------------------------------------------------------
// K3: finalize. 256 threads, fp64, fixed-order -> deterministic scalar.
// ---------------------------------------------------------------------------
__global__ __launch_bounds__(256) void finalize_kernel(
    const float* __restrict__ partials, float* __restrict__ out)
{
    __shared__ double sB[4], sM[4];
    __shared__ double sw_[NB], si_[NB], su_[NB];

    const int t = threadIdx.x;
    const int i = t >> 3;                 // image
    const int s = t & 7;

    double Sw=0, Si=0, Su=0, Bc=0, Ma=0;
    for (int k = s; k < CPI; k += 8) {
        const int bid = (i & 7) + (((i >> 3) * CPI + k) << 3);
        const float* pp = partials + (size_t)bid * 8;
        Sw += (double)pp[0]; Si += (double)pp[1]; Su += (double)pp[2];
        Bc += (double)pp[3]; Ma += (double)pp[4];
    }
    // group-of-8 reduce (groups aligned within a wave)
    #pragma unroll
    for (int d = 4; d >= 1; d >>= 1) {
        Sw += __shfl_down(Sw, d);
        Si += __shfl_down(Si, d);
        Su += __shfl_down(Su, d);
    }
    if (s == 0) { sw_[i] = Sw; si_[i] = Si; su_[i] = Su; }

    // full-wave reduce of global bce/mae partials
    #pragma unroll
    for (int d = 32; d >= 1; d >>= 1) {
        Bc += __shfl_down(Bc, d);
        Ma += __shfl_down(Ma, d);
    }
    if ((t & 63) == 0) { sB[t >> 6] = Bc; sM[t >> 6] = Ma; }
    __syncthreads();

    if (t < 64) {
        double wiou = 0.0, ratio = 0.0;
        if (t < NB) {
            const double w = sw_[t], ii = si_[t], u = su_[t];
            wiou  = 1.0 - ii / (u - ii);
            ratio = w / (w - (double)NPIX);
        }
        #pragma unroll
        for (int d = 32; d >= 1; d >>= 1) {
            wiou  += __shfl_down(wiou,  d);
            ratio += __shfl_down(ratio, d);
        }
        if (t == 0) {
            const double bt  = sB[0]+sB[1]+sB[2]+sB[3];
            const double mt  = sM[0]+sM[1]+sM[2]+sM[3];
            const double tot = (double)NB * (double)NPIX;
            const double bce = bt / tot;
            const double mae = mt / tot;
            out[0] = (float)(0.7 * (bce + wiou/(double)NB + mae * ratio/(double)NB));
        }
    }
}

extern "C" void kernel_launch(void* const* d_in, const int* in_sizes, int n_in,
                              void* d_out, int out_size, void* d_ws, size_t ws_size,
                              hipStream_t stream) {
    const float* pred = (const float*)d_in[0];
    const float* mask = (const float*)d_in[1];
    float* out        = (float*)d_out;

    float* S        = (float*)d_ws;                                   // 18.87 MB
    float* partials = (float*)((char*)d_ws + (size_t)NB*NPIX*sizeof(float));

    band_prefix_kernel<<<dim3(NBLK1), dim3(384), 0, stream>>>(mask, S);
    loss_kernel<<<dim3(NBLK2), dim3(256), 0, stream>>>(pred, mask, S, partials);
    finalize_kernel<<<dim3(1), dim3(256), 0, stream>>>(partials, out);
}